// Round 13
// baseline (8665.427 us; speedup 1.0000x reference)
//
#include <hip/hip_runtime.h>
#include <stdint.h>

#define LSEQ 1024
#define NB   64
#define DM   1024
#define FOURD 4096

typedef float f32x4 __attribute__((ext_vector_type(4)));
typedef short short8_t __attribute__((ext_vector_type(8)));
typedef __bf16 bf16x8 __attribute__((ext_vector_type(8)));
typedef unsigned int uint2v __attribute__((ext_vector_type(2)));
typedef unsigned int uint4v __attribute__((ext_vector_type(4)));

__device__ __forceinline__ unsigned short f2bf(float f) {
    unsigned int u = __builtin_bit_cast(unsigned int, f);
    u += 0x7fffu + ((u >> 16) & 1u);   // RNE
    return (unsigned short)(u >> 16);
}

__device__ __forceinline__ f32x4 mfma16(short8_t a, short8_t b, f32x4 c) {
    return __builtin_amdgcn_mfma_f32_16x16x32_bf16(
        __builtin_bit_cast(bf16x8, a), __builtin_bit_cast(bf16x8, b), c, 0, 0, 0);
}

__global__ void init_ws_kernel(unsigned int* __restrict__ p, int n) {
    int i = blockIdx.x * blockDim.x + threadIdx.x;
    int stride = gridDim.x * blockDim.x;
    for (; i < n; i += stride) p[i] = 0u;
}

// 8 f32 -> 8 bf16 per thread.
__global__ void convert_x_kernel(const float4* __restrict__ src, uint4* __restrict__ dst) {
    size_t i = (size_t)blockIdx.x * blockDim.x + threadIdx.x;
    float4 a = src[2 * i];
    float4 b = src[2 * i + 1];
    uint4 r;
    r.x = (unsigned)f2bf(a.x) | ((unsigned)f2bf(a.y) << 16);
    r.y = (unsigned)f2bf(a.z) | ((unsigned)f2bf(a.w) << 16);
    r.z = (unsigned)f2bf(b.x) | ((unsigned)f2bf(b.y) << 16);
    r.w = (unsigned)f2bf(b.z) | ((unsigned)f2bf(b.w) << 16);
    dst[i] = r;
}

// W [1024][4096] f32 -> wp: frag-ordered bf16 for the scan's register B-frags.
// fid bits: lane(6) | kk(2) | q(2) | ks(3) | ug(6).
// wp[fid][j] = bf16(W[ks*128 + kk*32 + (lane>>4)*8 + j][q*1024 + ug*16 + (lane&15)])
__global__ void prep_w_kernel(const float* __restrict__ W,
                              unsigned short* __restrict__ wp) {
    const int fid = blockIdx.x * 256 + threadIdx.x;   // 524288 frags
    const int lane = fid & 63;
    const int kk = (fid >> 6) & 3;
    const int q  = (fid >> 8) & 3;
    const int ks = (fid >> 10) & 7;
    const int ug = fid >> 13;
    const int k0 = (ks << 7) + (kk << 5) + ((lane >> 4) << 3);
    const int col = (q << 10) + (ug << 4) + (lane & 15);
    short8_t v;
    #pragma unroll
    for (int j = 0; j < 8; ++j)
        v[j] = (short)f2bf(W[(size_t)(k0 + j) * FOURD + col]);
    *(short8_t*)(wp + ((size_t)fid << 3)) = v;
}

// ---- load / wait macros ----
#define HL(arr, i, OFFS)                                                        \
    asm volatile("global_load_dwordx4 %0, %1, off offset:" OFFS " sc0 sc1"      \
                 : "=v"(arr[i]) : "v"(hap) : "memory")
#define XL(arr, i, OFFS)                                                        \
    asm volatile("global_load_dwordx4 %0, %1, off offset:" OFFS                 \
                 : "=v"(arr[i]) : "v"(xap) : "memory")
#define WAITV(NSTR)                                          \
    asm volatile("s_waitcnt vmcnt(" NSTR ")" ::: "memory");  \
    __builtin_amdgcn_sched_barrier(0)
#define WAITL()                                              \
    asm volatile("s_waitcnt lgkmcnt(0)" ::: "memory")
#define BARRIER()                                            \
    __builtin_amdgcn_s_barrier();                            \
    asm volatile("" ::: "memory")

// tagged-h load: 8x dwordx4 of {pair,tag,pair,tag} records
#define HT(i, OFFS)                                                             \
    asm volatile("global_load_dwordx4 %0, %1, off offset:" OFFS " sc0 sc1"      \
                 : "=v"(T[i]) : "v"(hap8) : "memory")
#define ISSUE8() { HT(0,"0");   HT(1,"16");  HT(2,"128"); HT(3,"144");          \
                   HT(4,"256"); HT(5,"272"); HT(6,"384"); HT(7,"400"); }
#define CHECKTAGS(okv, tgt) {                                                   \
    okv = 1;                                                                    \
    _Pragma("unroll")                                                           \
    for (int f_ = 0; f_ < 8; ++f_)                                              \
        okv &= (T[f_][1] >= (tgt)) & (T[f_][3] >= (tgt)); }

// ---------------- fused persistent LSTM scan (r7 base + tagged-h exchange) --
// 256 WGs x 512 thr (8 waves), 1 WG/CU via waves_per_eu(2,2). XCD mapping:
// rg=(wg&7)>>1, ug=(wg>>3)|((wg&1)<<5). WG (rg,ug): rows [16rg,+16), units
// [16ug,+16). Wave ks owns k [128ks,+128).
// SELF-VALIDATING h exchange: hbuf[2][64][512] of 8B records {2xbf16, tag}.
// 8B aligned single-instruction store/load = single-copy atomic -> no tearing.
// Producer: ONE dwordx2 sc0 sc1 store per unit-pair, tag = t+1. No ack, no
// flag, no barrier C (plds double-buffered; 2-barrier separation by induction).
// Consumer: poll IS the data load — 8 tagged dwordx4, x-MFMA overlapped, tag
// check (>= t), s_sleep(1) retry. Max skew = 1 step (proof: WG at t+2 needs
// h[t+1] incl. the lagging WG's own output) -> parity+tags never alias.
__global__ __launch_bounds__(512)
__attribute__((amdgpu_waves_per_eu(2, 2)))
void lstm_scan_kernel(const unsigned short* __restrict__ wip,
                      const unsigned short* __restrict__ whp,
                      const float* __restrict__ bias,
                      const unsigned short* __restrict__ xb,   // [L][64][1024] bf16
                      unsigned int* __restrict__ hbuf,         // [2][64][512][2] u32
                      float* __restrict__ out)                 // [L][N][D] f32
{
    __shared__ float plds[2][8][4][16][20];   // double-buffered partials, 80KB
    const int tid = threadIdx.x;
    const int wg = blockIdx.x;
    const int rg = (wg & 7) >> 1;                    // XCD pair -> row group
    const int ug = (wg >> 3) | ((wg & 1) << 5);      // bijective with rg
    const int r0 = rg << 4, U0 = ug << 4;
    const int lane = tid & 63, ks = tid >> 6;        // ks = wave 0..7
    const int la = lane & 15, kseg = lane >> 4;

    // ---- one-time: Wi/Wh fragments -> 128 registers ----
    short8_t BI[4][4], BH[4][4];
    {
        const unsigned short* wb = wip + (((size_t)(ug << 3) + ks) << 13);
        const unsigned short* hb = whp + (((size_t)(ug << 3) + ks) << 13);
        #pragma unroll
        for (int q = 0; q < 4; ++q)
            #pragma unroll
            for (int kk = 0; kk < 4; ++kk) {
                BI[q][kk] = *(const short8_t*)(wb + ((((q << 2) + kk) << 6) + lane) * 8);
                BH[q][kk] = *(const short8_t*)(hb + ((((q << 2) + kk) << 6) + lane) * 8);
            }
    }

    const int aoff = (r0 + la) * DM + (ks << 7) + (kseg << 3);
    // tagged-record base (pairs): row r0+la, pair index ks*64 + kseg*4
    const size_t poff = ((size_t)(r0 + la) * 512 + (ks << 6) + (kseg << 2)) * 8;

    // epilogue mapping (threads 0..255): row er, unit eu
    const int er = tid >> 4, eu = tid & 15;
    const float bI = bias[U0 + eu], bF = bias[1024 + U0 + eu],
                bG = bias[2048 + U0 + eu], bO = bias[3072 + U0 + eu];
    float cst = 0.0f;

    // prologue: x frags for t=0
    short8_t xf[4];
    {
        const unsigned short* xap = xb + aoff;
        XL(xf, 0, "0"); XL(xf, 1, "64"); XL(xf, 2, "128"); XL(xf, 3, "192");
        asm volatile("s_waitcnt vmcnt(0)" ::: "memory");
        __builtin_amdgcn_sched_barrier(0);
    }

    for (int t = 0; t < LSEQ; ++t) {
        // (a) issue 8 tagged h-record loads (consumer's disjoint k-slice)
        uint4v T[8];
        const char* hap8 = (const char*)hbuf
            + (size_t)((t & 1) ^ 1) * (64 * 512 * 8) + poff;
        ISSUE8();
        // (b) retire everything older (XL(t), h/out stores) -> xf valid
        WAITV("8");

        // (c) x-part MFMA — overlaps the tagged-load L3 latency
        f32x4 acc[4];
        #pragma unroll
        for (int q = 0; q < 4; ++q) acc[q] = (f32x4){0.f, 0.f, 0.f, 0.f};
        #pragma unroll
        for (int kk = 0; kk < 4; ++kk)
            #pragma unroll
            for (int q = 0; q < 4; ++q)
                acc[q] = mfma16(xf[kk], BI[q][kk], acc[q]);

        // (d) tagged data in regs; validate (t=0 consumes zeros, no check)
        WAITV("0");
        if (t) {
            const unsigned tgt = (unsigned)t;
            int ok; CHECKTAGS(ok, tgt);
            while (!__all(ok)) {
                __builtin_amdgcn_s_sleep(1);
                ISSUE8();
                WAITV("0");
                CHECKTAGS(ok, tgt);
            }
        }

        // (e) unpack pairs -> h A-frags, h-part MFMA
        #pragma unroll
        for (int f = 0; f < 4; ++f) {
            uint4v hv4 = {T[2 * f][0], T[2 * f][2], T[2 * f + 1][0], T[2 * f + 1][2]};
            short8_t hf = __builtin_bit_cast(short8_t, hv4);
            #pragma unroll
            for (int q = 0; q < 4; ++q)
                acc[q] = mfma16(hf, BH[q][f], acc[q]);
        }

        // (f) partials -> plds[t&1]; the ONLY barrier of the step
        #pragma unroll
        for (int q = 0; q < 4; ++q)
            *(f32x4*)&plds[t & 1][ks][q][la][kseg << 2] = acc[q];
        WAITL();
        BARRIER();

        // (g) epilogue on waves 0-3: reduce 8 K-partials, gates, c/h update
        float hv = 0.f, hn = 0.f;
        if (tid < 256) {
            float vi = bI, vf = bF, vg = bG, vo = bO;
            #pragma unroll
            for (int s = 0; s < 8; ++s) {
                vi += plds[t & 1][s][0][eu][er];
                vf += plds[t & 1][s][1][eu][er];
                vg += plds[t & 1][s][2][eu][er];
                vo += plds[t & 1][s][3][eu][er];
            }
            float gi = 1.0f / (1.0f + __expf(-vi));
            float gF = 1.0f / (1.0f + __expf(-vf));
            float gg = 1.0f - 2.0f / (__expf(2.0f * vg) + 1.0f);
            float go = 1.0f / (1.0f + __expf(-vo));
            cst = gF * cst + gi * gg;
            hv = go * (1.0f - 2.0f / (__expf(2.0f * cst) + 1.0f));
            hn = __shfl_xor(hv, 1);   // partner unit eu^1

            // (h) single tagged 8B store — fire and forget
            if (!(eu & 1)) {
                unsigned int hp = (unsigned)f2bf(hv) | ((unsigned)f2bf(hn) << 16);
                uint2v pv = {hp, (unsigned)(t + 1)};
                unsigned int* hw = hbuf + (size_t)(t & 1) * (64 * 512 * 2)
                                 + (((size_t)(r0 + er) * 512 + ((U0 + eu) >> 1)) << 1);
                asm volatile("global_store_dwordx2 %0, %1, off sc0 sc1"
                             :: "v"(hw), "v"(pv) : "memory");
            }
        }

        // (i) issue X(t+1) prefetch (retired by next step's WAITV(8))
        {
            const int tn = (t < LSEQ - 1) ? t + 1 : t;
            const unsigned short* xap = xb + (size_t)tn * (NB * DM) + aoff;
            XL(xf, 0, "0"); XL(xf, 1, "64"); XL(xf, 2, "128"); XL(xf, 3, "192");
        }

        // (j) out store — plain, off the critical chain
        if (tid < 256 && !(eu & 1))
            *(float2*)(out + ((size_t)(t * NB) + r0 + er) * DM + U0 + eu)
                = make_float2(hv, hn);
    }
}

// ---------------- fallback (only if ws too small; r2-proven) ----------------
#define HM(arr, i, kk) {                                        \
    short8_t b = *(const short8_t*)(bph + (kk) * 1024);         \
    if ((kk) & 1) acc1 = mfma16(arr[i], b, acc1);               \
    else          acc0 = mfma16(arr[i], b, acc0); }

__global__ __launch_bounds__(256)
void lstm_fallback_kernel(const float* __restrict__ x,
                          const float* __restrict__ Wi,
                          const float* __restrict__ Wh,
                          const float* __restrict__ bias,
                          unsigned short* __restrict__ hbuf,
                          unsigned int* __restrict__ flags,
                          float* __restrict__ out)
{
    __shared__ short Wlds[65536];
    __shared__ float ylds[32 * 33];
    __shared__ float blds[32];

    const int tid  = threadIdx.x;
    const int wgid = blockIdx.x;
    const int g    = wgid >> 7;
    const int ug   = wgid & 127;
    const int U0   = ug << 3;
    const int rowbase = g << 5;

    {
        const int c    = tid & 31;
        const int ct_  = c >> 4;
        const int lb   = c & 15;
        const int gcol = ((c >> 3) << 10) + U0 + (c & 7);
        for (int k = tid >> 5; k < 1024; k += 8) {
            const int lane_ = lb | (((k >> 3) & 3) << 4);
            const int sidx  = (ct_ * 32 + (k >> 5)) * 512 + lane_ * 8 + (k & 7);
            Wlds[sidx]         = (short)f2bf(Wi[(size_t)k * FOURD + gcol]);
            Wlds[sidx + 32768] = (short)f2bf(Wh[(size_t)k * FOURD + gcol]);
        }
        if (tid < 32) blds[tid] = bias[((tid >> 3) << 10) + U0 + (tid & 7)];
    }
    __syncthreads();

    const int lane = tid & 63;
    const int wv   = tid >> 6;
    const int rt   = wv >> 1;
    const int ct   = wv & 1;
    const int arow = rowbase + (rt << 4) + (lane & 15);
    const int kseg = (lane >> 4) << 3;
    const char* bpx = (const char*)Wlds + ct * 32768 + lane * 16;
    const char* bph = (const char*)Wlds + 65536 + ct * 32768 + lane * 16;

    const int er = tid >> 3;
    const int eu = tid & 7;
    const float bI = blds[eu], bF = blds[8 + eu], bG = blds[16 + eu], bO = blds[24 + eu];
    float cstate = 0.0f;
    unsigned int* gflags = flags + (g << 7);

    for (int t = 0; t < LSEQ; ++t) {
        f32x4 acc0 = {0.f, 0.f, 0.f, 0.f};
        f32x4 acc1 = {0.f, 0.f, 0.f, 0.f};

        {
            const float* ap = x + ((size_t)t * NB + arow) * DM + kseg;
            #pragma unroll 4
            for (int kk = 0; kk < 32; ++kk) {
                float4 lo = *(const float4*)(ap + kk * 32);
                float4 hi = *(const float4*)(ap + kk * 32 + 4);
                short8_t a;
                a[0] = (short)f2bf(lo.x); a[1] = (short)f2bf(lo.y);
                a[2] = (short)f2bf(lo.z); a[3] = (short)f2bf(lo.w);
                a[4] = (short)f2bf(hi.x); a[5] = (short)f2bf(hi.y);
                a[6] = (short)f2bf(hi.z); a[7] = (short)f2bf(hi.w);
                short8_t b = *(const short8_t*)(bpx + kk * 1024);
                if (kk & 1) acc1 = mfma16(a, b, acc1);
                else        acc0 = mfma16(a, b, acc0);
            }
        }

        if (t && wv == 0) {
            const unsigned int* fp = gflags + (lane << 1);
            while (true) {
                unsigned int f0 = __hip_atomic_load(fp,     __ATOMIC_RELAXED, __HIP_MEMORY_SCOPE_AGENT);
                unsigned int f1 = __hip_atomic_load(fp + 1, __ATOMIC_RELAXED, __HIP_MEMORY_SCOPE_AGENT);
                int ok = (f0 >= (unsigned)t) && (f1 >= (unsigned)t);
                if (__all(ok)) break;
                __builtin_amdgcn_s_sleep(1);
            }
        }
        __syncthreads();

        {
            const unsigned short* hap =
                hbuf + (size_t)((t & 1) ^ 1) * (NB * DM) + (size_t)arow * DM + kseg;
            short8_t A0[8], A1[8];
            HL(A0,0,"0");    HL(A0,1,"64");   HL(A0,2,"128");  HL(A0,3,"192");
            HL(A0,4,"256");  HL(A0,5,"320");  HL(A0,6,"384");  HL(A0,7,"448");
            HL(A1,0,"512");  HL(A1,1,"576");  HL(A1,2,"640");  HL(A1,3,"704");
            HL(A1,4,"768");  HL(A1,5,"832");  HL(A1,6,"896");  HL(A1,7,"960");
            WAITV("8");
            HM(A0,0,0)  HM(A0,1,1)  HM(A0,2,2)  HM(A0,3,3)
            HM(A0,4,4)  HM(A0,5,5)  HM(A0,6,6)  HM(A0,7,7)
            HL(A0,0,"1024"); HL(A0,1,"1088"); HL(A0,2,"1152"); HL(A0,3,"1216");
            HL(A0,4,"1280"); HL(A0,5,"1344"); HL(A0,6,"1408"); HL(A0,7,"1472");
            WAITV("8");
            HM(A1,0,8)  HM(A1,1,9)  HM(A1,2,10) HM(A1,3,11)
            HM(A1,4,12) HM(A1,5,13) HM(A1,6,14) HM(A1,7,15)
            HL(A1,0,"1536"); HL(A1,1,"1600"); HL(A1,2,"1664"); HL(A1,3,"1728");
            HL(A1,4,"1792"); HL(A1,5,"1856"); HL(A1,6,"1920"); HL(A1,7,"1984");
            WAITV("8");
            HM(A0,0,16) HM(A0,1,17) HM(A0,2,18) HM(A0,3,19)
            HM(A0,4,20) HM(A0,5,21) HM(A0,6,22) HM(A0,7,23)
            WAITV("0");
            HM(A1,0,24) HM(A1,1,25) HM(A1,2,26) HM(A1,3,27)
            HM(A1,4,28) HM(A1,5,29) HM(A1,6,30) HM(A1,7,31)
        }

        {
            f32x4 acc = acc0 + acc1;
            const int rr0 = (rt << 4) + ((lane >> 4) << 2);
            const int c0 = (ct << 4) + (lane & 15);
            #pragma unroll
            for (int j = 0; j < 4; ++j) ylds[(rr0 + j) * 33 + c0] = acc[j];
        }
        __syncthreads();

        {
            const float* yr = ylds + er * 33;
            float vi = yr[eu]      + bI;
            float vf = yr[8 + eu]  + bF;
            float vg = yr[16 + eu] + bG;
            float vo = yr[24 + eu] + bO;
            float gi = 1.0f / (1.0f + __expf(-vi));
            float gF = 1.0f / (1.0f + __expf(-vf));
            float gg = 1.0f - 2.0f / (__expf(2.0f * vg) + 1.0f);
            float go = 1.0f / (1.0f + __expf(-vo));
            cstate = gF * cstate + gi * gg;
            float hv = go * (1.0f - 2.0f / (__expf(2.0f * cstate) + 1.0f));
            float hvn = __shfl_down(hv, 1);
            if ((tid & 1) == 0) {
                const int n = rowbase + er;
                const int d = U0 + eu;
                unsigned int hp = (unsigned)f2bf(hv) | ((unsigned)f2bf(hvn) << 16);
                unsigned int* hw = (unsigned int*)(hbuf + (size_t)(t & 1) * (NB * DM)
                                                   + (size_t)n * DM + d);
                __hip_atomic_store(hw, hp, __ATOMIC_RELAXED, __HIP_MEMORY_SCOPE_AGENT);
                *(float2*)(out + ((size_t)t * NB + n) * DM + d) = make_float2(hv, hvn);
            }
        }
        asm volatile("s_waitcnt vmcnt(0)" ::: "memory");
        __syncthreads();

        if (tid == 0) {
            __hip_atomic_store(gflags + ug, (unsigned)(t + 1),
                               __ATOMIC_RELAXED, __HIP_MEMORY_SCOPE_AGENT);
            asm volatile("s_waitcnt vmcnt(0)" ::: "memory");
        }
    }
}

extern "C" void kernel_launch(void* const* d_in, const int* in_sizes, int n_in,
                              void* d_out, int out_size, void* d_ws, size_t ws_size,
                              hipStream_t stream) {
    (void)in_sizes; (void)n_in; (void)out_size;
    const float* x  = (const float*)d_in[0];
    const float* Wi = (const float*)d_in[1];
    const float* Wh = (const float*)d_in[2];
    const float* b  = (const float*)d_in[3];
    float* out = (float*)d_out;

    char* ws = (char*)d_ws;
    // layout: flags(4K, fallback only) | hbuf(512K tagged) | wip(8M) | whp(8M)
    //         | xb(128M)   ~= 145 MB
    const size_t OFF_HB  = 4096;
    const size_t OFF_WIP = OFF_HB + 524288;            // 528,384
    const size_t OFF_WHP = OFF_WIP + 8388608ull;
    const size_t OFF_XB  = OFF_WHP + 8388608ull;       // 17,305,600
    const size_t NEED    = OFF_XB + 134217728ull;

    unsigned int* flags = (unsigned int*)ws;
    unsigned int* hbuf  = (unsigned int*)(ws + OFF_HB);

    // zero flags + tagged hbuf every call (tags must start at 0)
    init_ws_kernel<<<64, 256, 0, stream>>>((unsigned int*)ws, 132096);

    if (ws_size >= NEED) {
        unsigned short* wip = (unsigned short*)(ws + OFF_WIP);
        unsigned short* whp = (unsigned short*)(ws + OFF_WHP);
        unsigned short* xb  = (unsigned short*)(ws + OFF_XB);
        convert_x_kernel<<<32768, 256, 0, stream>>>((const float4*)x, (uint4*)xb);
        prep_w_kernel<<<2048, 256, 0, stream>>>(Wi, wip);
        prep_w_kernel<<<2048, 256, 0, stream>>>(Wh, whp);
        lstm_scan_kernel<<<256, 512, 0, stream>>>(wip, whp, b, xb, hbuf, out);
    } else {
        lstm_fallback_kernel<<<256, 256, 0, stream>>>(x, Wi, Wh, b,
                                                      (unsigned short*)(ws + OFF_HB),
                                                      flags, out);
    }
}

// Round 14
// 3768.033 us; speedup vs baseline: 2.2997x; 2.2997x over previous
//
#include <hip/hip_runtime.h>
#include <stdint.h>

#define LSEQ 1024
#define NB   64
#define DM   1024
#define FOURD 4096

typedef float f32x4 __attribute__((ext_vector_type(4)));
typedef short short8_t __attribute__((ext_vector_type(8)));
typedef __bf16 bf16x8 __attribute__((ext_vector_type(8)));

__device__ __forceinline__ unsigned short f2bf(float f) {
    unsigned int u = __builtin_bit_cast(unsigned int, f);
    u += 0x7fffu + ((u >> 16) & 1u);   // RNE
    return (unsigned short)(u >> 16);
}

__device__ __forceinline__ f32x4 mfma16(short8_t a, short8_t b, f32x4 c) {
    return __builtin_amdgcn_mfma_f32_16x16x32_bf16(
        __builtin_bit_cast(bf16x8, a), __builtin_bit_cast(bf16x8, b), c, 0, 0, 0);
}

__global__ void init_ws_kernel(unsigned int* __restrict__ p, int n) {
    int i = blockIdx.x * blockDim.x + threadIdx.x;
    int stride = gridDim.x * blockDim.x;
    for (; i < n; i += stride) p[i] = 0u;
}

// 8 f32 -> 8 bf16 per thread.
__global__ void convert_x_kernel(const float4* __restrict__ src, uint4* __restrict__ dst) {
    size_t i = (size_t)blockIdx.x * blockDim.x + threadIdx.x;
    float4 a = src[2 * i];
    float4 b = src[2 * i + 1];
    uint4 r;
    r.x = (unsigned)f2bf(a.x) | ((unsigned)f2bf(a.y) << 16);
    r.y = (unsigned)f2bf(a.z) | ((unsigned)f2bf(a.w) << 16);
    r.z = (unsigned)f2bf(b.x) | ((unsigned)f2bf(b.y) << 16);
    r.w = (unsigned)f2bf(b.z) | ((unsigned)f2bf(b.w) << 16);
    dst[i] = r;
}

// W [1024][4096] f32 -> wp: frag-ordered bf16 for the scan's register B-frags.
// fid bits: lane(6) | kk(2) | q(2) | ks(3) | ug(6).
// wp[fid][j] = bf16(W[ks*128 + kk*32 + (lane>>4)*8 + j][q*1024 + ug*16 + (lane&15)])
__global__ void prep_w_kernel(const float* __restrict__ W,
                              unsigned short* __restrict__ wp) {
    const int fid = blockIdx.x * 256 + threadIdx.x;   // 524288 frags
    const int lane = fid & 63;
    const int kk = (fid >> 6) & 3;
    const int q  = (fid >> 8) & 3;
    const int ks = (fid >> 10) & 7;
    const int ug = fid >> 13;
    const int k0 = (ks << 7) + (kk << 5) + ((lane >> 4) << 3);
    const int col = (q << 10) + (ug << 4) + (lane & 15);
    short8_t v;
    #pragma unroll
    for (int j = 0; j < 8; ++j)
        v[j] = (short)f2bf(W[(size_t)(k0 + j) * FOURD + col]);
    *(short8_t*)(wp + ((size_t)fid << 3)) = v;
}

// ---- load / wait macros ----
#define HL(arr, i, OFFS)                                                        \
    asm volatile("global_load_dwordx4 %0, %1, off offset:" OFFS " sc0 sc1"      \
                 : "=v"(arr[i]) : "v"(hap) : "memory")
#define XL(arr, i, OFFS)                                                        \
    asm volatile("global_load_dwordx4 %0, %1, off offset:" OFFS                 \
                 : "=v"(arr[i]) : "v"(xap) : "memory")
#define WAITV(NSTR)                                          \
    asm volatile("s_waitcnt vmcnt(" NSTR ")" ::: "memory");  \
    __builtin_amdgcn_sched_barrier(0)
#define WAITL()                                              \
    asm volatile("s_waitcnt lgkmcnt(0)" ::: "memory")
#define BARRIER()                                            \
    __builtin_amdgcn_s_barrier();                            \
    asm volatile("" ::: "memory")

// ---------------- fused persistent LSTM scan (r11 — best measured) ----------
// 256 WGs x 512 thr (8 waves), 1 WG/CU via waves_per_eu(2,2). XCD mapping:
// rg=(wg&7)>>1, ug=(wg>>3)|((wg&1)<<5). WG (rg,ug): rows [16rg,+16), units
// [16ug,+16). Wave ks owns k [128ks,+128); its h-slice depends on only 8
// producer WGs (ug in [8ks,8ks+8)). Each wave polls its own 8 producer flags
// (s_sleep(1) throttle); no barrier A. Two barriers/step (B, C). Weights in
// 128 regs; x prefetched one step ahead; counted vmcnt throughout.
__global__ __launch_bounds__(512)
__attribute__((amdgpu_waves_per_eu(2, 2)))
void lstm_scan_kernel(const unsigned short* __restrict__ wip,
                      const unsigned short* __restrict__ whp,
                      const float* __restrict__ bias,
                      const unsigned short* __restrict__ xb,   // [L][64][1024] bf16
                      unsigned short* __restrict__ hbuf,       // [2][64][1024] bf16
                      unsigned int* __restrict__ flags,        // [4][64]
                      float* __restrict__ out)                 // [L][N][D] f32
{
    __shared__ float plds[8][4][16][20];   // [ks][q][unit][row pad20] 40KB
    const int tid = threadIdx.x;
    const int wg = blockIdx.x;
    const int rg = (wg & 7) >> 1;                    // XCD pair -> row group
    const int ug = (wg >> 3) | ((wg & 1) << 5);      // bijective with rg
    const int r0 = rg << 4, U0 = ug << 4;
    const int lane = tid & 63, ks = tid >> 6;        // ks = wave 0..7
    const int la = lane & 15, kseg = lane >> 4;

    // ---- one-time: Wi/Wh fragments -> 128 registers ----
    short8_t BI[4][4], BH[4][4];
    {
        const unsigned short* wb = wip + (((size_t)(ug << 3) + ks) << 13);
        const unsigned short* hb = whp + (((size_t)(ug << 3) + ks) << 13);
        #pragma unroll
        for (int q = 0; q < 4; ++q)
            #pragma unroll
            for (int kk = 0; kk < 4; ++kk) {
                BI[q][kk] = *(const short8_t*)(wb + ((((q << 2) + kk) << 6) + lane) * 8);
                BH[q][kk] = *(const short8_t*)(hb + ((((q << 2) + kk) << 6) + lane) * 8);
            }
    }

    const int aoff = (r0 + la) * DM + (ks << 7) + (kseg << 3);

    // epilogue mapping (threads 0..255): row er, unit eu
    const int er = tid >> 4, eu = tid & 15;
    const float bI = bias[U0 + eu], bF = bias[1024 + U0 + eu],
                bG = bias[2048 + U0 + eu], bO = bias[3072 + U0 + eu];
    float cst = 0.0f;
    unsigned int* myflag = flags + (rg << 6) + ug;
    // per-wave poll: wave ks depends on producer WGs ug' in [8ks, 8ks+8)
    const unsigned int* gfp = flags + (rg << 6) + (ks << 3) + (lane & 7);

    // prologue: x frags for t=0
    short8_t xf[4];
    {
        const unsigned short* xap = xb + aoff;
        XL(xf, 0, "0"); XL(xf, 1, "64"); XL(xf, 2, "128"); XL(xf, 3, "192");
        asm volatile("s_waitcnt vmcnt(0)" ::: "memory");
        __builtin_amdgcn_sched_barrier(0);
    }

    for (int t = 0; t < LSEQ; ++t) {
        // (a) per-wave poll: my 8 producer WGs posted step t-1 (throttled)
        if (t) {
            while (true) {
                unsigned int f = __hip_atomic_load(gfp, __ATOMIC_RELAXED,
                                                   __HIP_MEMORY_SCOPE_AGENT);
                if (__all((int)(f >= (unsigned)t))) break;
                __builtin_amdgcn_s_sleep(1);
            }
        }
        // (no barrier A — this wave proceeds as soon as ITS producers are done)

        // (b) issue coherent h loads (per-wave disjoint K)
        short8_t hf[4];
        {
            const unsigned short* hap =
                hbuf + (size_t)((t & 1) ^ 1) * (NB * DM) + aoff;
            HL(hf, 0, "0"); HL(hf, 1, "64"); HL(hf, 2, "128"); HL(hf, 3, "192");
        }
        // (c) retire everything older than the 4 HL (out-store, flag, XL(t))
        WAITV("4");

        // (d) x-part MFMA — overlaps the h-load L3 latency
        f32x4 acc[4];
        #pragma unroll
        for (int q = 0; q < 4; ++q) acc[q] = (f32x4){0.f, 0.f, 0.f, 0.f};
        #pragma unroll
        for (int kk = 0; kk < 4; ++kk)
            #pragma unroll
            for (int q = 0; q < 4; ++q)
                acc[q] = mfma16(xf[kk], BI[q][kk], acc[q]);

        // (e) h frags ready
        WAITV("0");

        // (f) h-part MFMA
        #pragma unroll
        for (int kk = 0; kk < 4; ++kk)
            #pragma unroll
            for (int q = 0; q < 4; ++q)
                acc[q] = mfma16(hf[kk], BH[q][kk], acc[q]);

        // (g) partials -> LDS, barrier B
        #pragma unroll
        for (int q = 0; q < 4; ++q)
            *(f32x4*)&plds[ks][q][la][kseg << 2] = acc[q];
        WAITL();
        BARRIER();   // B: plds produced (all waves)

        // (h) epilogue on waves 0-3: reduce 8 K-partials, gates, c/h update
        float hv = 0.f, hn = 0.f;
        if (tid < 256) {
            float vi = bI, vf = bF, vg = bG, vo = bO;
            #pragma unroll
            for (int s = 0; s < 8; ++s) {
                vi += plds[s][0][eu][er];
                vf += plds[s][1][eu][er];
                vg += plds[s][2][eu][er];
                vo += plds[s][3][eu][er];
            }
            float gi = 1.0f / (1.0f + __expf(-vi));
            float gF = 1.0f / (1.0f + __expf(-vf));
            float gg = 1.0f - 2.0f / (__expf(2.0f * vg) + 1.0f);
            float go = 1.0f / (1.0f + __expf(-vo));
            cst = gF * cst + gi * gg;
            hv = go * (1.0f - 2.0f / (__expf(2.0f * cst) + 1.0f));
            hn = __shfl_xor(hv, 1);   // partner unit eu^1

            // (i) coherent h-store
            if (!(eu & 1)) {
                unsigned int hp = (unsigned)f2bf(hv) | ((unsigned)f2bf(hn) << 16);
                unsigned int* hw = (unsigned int*)(hbuf + (size_t)(t & 1) * (NB * DM)
                                                   + (size_t)(r0 + er) * DM + U0 + eu);
                asm volatile("global_store_dword %0, %1, off sc0 sc1"
                             :: "v"(hw), "v"(hp) : "memory");
            }
        }

        // (j) issue X(t+1) prefetch (all waves; after h-store in program order)
        {
            const int tn = (t < LSEQ - 1) ? t + 1 : t;
            const unsigned short* xap = xb + (size_t)tn * (NB * DM) + aoff;
            XL(xf, 0, "0"); XL(xf, 1, "64"); XL(xf, 2, "128"); XL(xf, 3, "192");
        }
        // (k) in-order retirement: <=4 outstanding => h-store done, XL flying
        WAITV("4");

        BARRIER();   // C: all waves' h-stores at L3; fences plds reuse

        // (m) single flag post per WG
        if (tid == 0)
            __hip_atomic_store(myflag, (unsigned)(t + 1), __ATOMIC_RELAXED,
                               __HIP_MEMORY_SCOPE_AGENT);

        // (n) out store — after the flag, off the critical chain
        if (tid < 256 && !(eu & 1))
            *(float2*)(out + ((size_t)(t * NB) + r0 + er) * DM + U0 + eu)
                = make_float2(hv, hn);
    }
}

// ---------------- fallback (only if ws too small; r2-proven) ----------------
#define HM(arr, i, kk) {                                        \
    short8_t b = *(const short8_t*)(bph + (kk) * 1024);         \
    if ((kk) & 1) acc1 = mfma16(arr[i], b, acc1);               \
    else          acc0 = mfma16(arr[i], b, acc0); }

__global__ __launch_bounds__(256)
void lstm_fallback_kernel(const float* __restrict__ x,
                          const float* __restrict__ Wi,
                          const float* __restrict__ Wh,
                          const float* __restrict__ bias,
                          unsigned short* __restrict__ hbuf,
                          unsigned int* __restrict__ flags,
                          float* __restrict__ out)
{
    __shared__ short Wlds[65536];
    __shared__ float ylds[32 * 33];
    __shared__ float blds[32];

    const int tid  = threadIdx.x;
    const int wgid = blockIdx.x;
    const int g    = wgid >> 7;
    const int ug   = wgid & 127;
    const int U0   = ug << 3;
    const int rowbase = g << 5;

    {
        const int c    = tid & 31;
        const int ct_  = c >> 4;
        const int lb   = c & 15;
        const int gcol = ((c >> 3) << 10) + U0 + (c & 7);
        for (int k = tid >> 5; k < 1024; k += 8) {
            const int lane_ = lb | (((k >> 3) & 3) << 4);
            const int sidx  = (ct_ * 32 + (k >> 5)) * 512 + lane_ * 8 + (k & 7);
            Wlds[sidx]         = (short)f2bf(Wi[(size_t)k * FOURD + gcol]);
            Wlds[sidx + 32768] = (short)f2bf(Wh[(size_t)k * FOURD + gcol]);
        }
        if (tid < 32) blds[tid] = bias[((tid >> 3) << 10) + U0 + (tid & 7)];
    }
    __syncthreads();

    const int lane = tid & 63;
    const int wv   = tid >> 6;
    const int rt   = wv >> 1;
    const int ct   = wv & 1;
    const int arow = rowbase + (rt << 4) + (lane & 15);
    const int kseg = (lane >> 4) << 3;
    const char* bpx = (const char*)Wlds + ct * 32768 + lane * 16;
    const char* bph = (const char*)Wlds + 65536 + ct * 32768 + lane * 16;

    const int er = tid >> 3;
    const int eu = tid & 7;
    const float bI = blds[eu], bF = blds[8 + eu], bG = blds[16 + eu], bO = blds[24 + eu];
    float cstate = 0.0f;
    unsigned int* gflags = flags + (g << 7);

    for (int t = 0; t < LSEQ; ++t) {
        f32x4 acc0 = {0.f, 0.f, 0.f, 0.f};
        f32x4 acc1 = {0.f, 0.f, 0.f, 0.f};

        {
            const float* ap = x + ((size_t)t * NB + arow) * DM + kseg;
            #pragma unroll 4
            for (int kk = 0; kk < 32; ++kk) {
                float4 lo = *(const float4*)(ap + kk * 32);
                float4 hi = *(const float4*)(ap + kk * 32 + 4);
                short8_t a;
                a[0] = (short)f2bf(lo.x); a[1] = (short)f2bf(lo.y);
                a[2] = (short)f2bf(lo.z); a[3] = (short)f2bf(lo.w);
                a[4] = (short)f2bf(hi.x); a[5] = (short)f2bf(hi.y);
                a[6] = (short)f2bf(hi.z); a[7] = (short)f2bf(hi.w);
                short8_t b = *(const short8_t*)(bpx + kk * 1024);
                if (kk & 1) acc1 = mfma16(a, b, acc1);
                else        acc0 = mfma16(a, b, acc0);
            }
        }

        if (t && wv == 0) {
            const unsigned int* fp = gflags + (lane << 1);
            while (true) {
                unsigned int f0 = __hip_atomic_load(fp,     __ATOMIC_RELAXED, __HIP_MEMORY_SCOPE_AGENT);
                unsigned int f1 = __hip_atomic_load(fp + 1, __ATOMIC_RELAXED, __HIP_MEMORY_SCOPE_AGENT);
                int ok = (f0 >= (unsigned)t) && (f1 >= (unsigned)t);
                if (__all(ok)) break;
                __builtin_amdgcn_s_sleep(1);
            }
        }
        __syncthreads();

        {
            const unsigned short* hap =
                hbuf + (size_t)((t & 1) ^ 1) * (NB * DM) + (size_t)arow * DM + kseg;
            short8_t A0[8], A1[8];
            HL(A0,0,"0");    HL(A0,1,"64");   HL(A0,2,"128");  HL(A0,3,"192");
            HL(A0,4,"256");  HL(A0,5,"320");  HL(A0,6,"384");  HL(A0,7,"448");
            HL(A1,0,"512");  HL(A1,1,"576");  HL(A1,2,"640");  HL(A1,3,"704");
            HL(A1,4,"768");  HL(A1,5,"832");  HL(A1,6,"896");  HL(A1,7,"960");
            WAITV("8");
            HM(A0,0,0)  HM(A0,1,1)  HM(A0,2,2)  HM(A0,3,3)
            HM(A0,4,4)  HM(A0,5,5)  HM(A0,6,6)  HM(A0,7,7)
            HL(A0,0,"1024"); HL(A0,1,"1088"); HL(A0,2,"1152"); HL(A0,3,"1216");
            HL(A0,4,"1280"); HL(A0,5,"1344"); HL(A0,6,"1408"); HL(A0,7,"1472");
            WAITV("8");
            HM(A1,0,8)  HM(A1,1,9)  HM(A1,2,10) HM(A1,3,11)
            HM(A1,4,12) HM(A1,5,13) HM(A1,6,14) HM(A1,7,15)
            HL(A1,0,"1536"); HL(A1,1,"1600"); HL(A1,2,"1664"); HL(A1,3,"1728");
            HL(A1,4,"1792"); HL(A1,5,"1856"); HL(A1,6,"1920"); HL(A1,7,"1984");
            WAITV("8");
            HM(A0,0,16) HM(A0,1,17) HM(A0,2,18) HM(A0,3,19)
            HM(A0,4,20) HM(A0,5,21) HM(A0,6,22) HM(A0,7,23)
            WAITV("0");
            HM(A1,0,24) HM(A1,1,25) HM(A1,2,26) HM(A1,3,27)
            HM(A1,4,28) HM(A1,5,29) HM(A1,6,30) HM(A1,7,31)
        }

        {
            f32x4 acc = acc0 + acc1;
            const int rr0 = (rt << 4) + ((lane >> 4) << 2);
            const int c0 = (ct << 4) + (lane & 15);
            #pragma unroll
            for (int j = 0; j < 4; ++j) ylds[(rr0 + j) * 33 + c0] = acc[j];
        }
        __syncthreads();

        {
            const float* yr = ylds + er * 33;
            float vi = yr[eu]      + bI;
            float vf = yr[8 + eu]  + bF;
            float vg = yr[16 + eu] + bG;
            float vo = yr[24 + eu] + bO;
            float gi = 1.0f / (1.0f + __expf(-vi));
            float gF = 1.0f / (1.0f + __expf(-vf));
            float gg = 1.0f - 2.0f / (__expf(2.0f * vg) + 1.0f);
            float go = 1.0f / (1.0f + __expf(-vo));
            cstate = gF * cstate + gi * gg;
            float hv = go * (1.0f - 2.0f / (__expf(2.0f * cstate) + 1.0f));
            float hvn = __shfl_down(hv, 1);
            if ((tid & 1) == 0) {
                const int n = rowbase + er;
                const int d = U0 + eu;
                unsigned int hp = (unsigned)f2bf(hv) | ((unsigned)f2bf(hvn) << 16);
                unsigned int* hw = (unsigned int*)(hbuf + (size_t)(t & 1) * (NB * DM)
                                                   + (size_t)n * DM + d);
                __hip_atomic_store(hw, hp, __ATOMIC_RELAXED, __HIP_MEMORY_SCOPE_AGENT);
                *(float2*)(out + ((size_t)t * NB + n) * DM + d) = make_float2(hv, hvn);
            }
        }
        asm volatile("s_waitcnt vmcnt(0)" ::: "memory");
        __syncthreads();

        if (tid == 0) {
            __hip_atomic_store(gflags + ug, (unsigned)(t + 1),
                               __ATOMIC_RELAXED, __HIP_MEMORY_SCOPE_AGENT);
            asm volatile("s_waitcnt vmcnt(0)" ::: "memory");
        }
    }
}

extern "C" void kernel_launch(void* const* d_in, const int* in_sizes, int n_in,
                              void* d_out, int out_size, void* d_ws, size_t ws_size,
                              hipStream_t stream) {
    (void)in_sizes; (void)n_in; (void)out_size;
    const float* x  = (const float*)d_in[0];
    const float* Wi = (const float*)d_in[1];
    const float* Wh = (const float*)d_in[2];
    const float* b  = (const float*)d_in[3];
    float* out = (float*)d_out;

    char* ws = (char*)d_ws;
    // layout: flags(4K) | hbuf(256K) | wip(8M) | whp(8M) | xb(128M)  ~= 151 MB
    const size_t OFF_HB  = 4096;
    const size_t OFF_WIP = OFF_HB + 262144;
    const size_t OFF_WHP = OFF_WIP + 8388608ull;
    const size_t OFF_XB  = OFF_WHP + 8388608ull;
    const size_t NEED    = OFF_XB + 134217728ull;

    unsigned int*   flags = (unsigned int*)ws;
    unsigned short* hbuf  = (unsigned short*)(ws + OFF_HB);

    // zero flags + hbuf every call (ws poisoned once, never restored)
    init_ws_kernel<<<64, 256, 0, stream>>>((unsigned int*)ws, 66560);

    if (ws_size >= NEED) {
        unsigned short* wip = (unsigned short*)(ws + OFF_WIP);
        unsigned short* whp = (unsigned short*)(ws + OFF_WHP);
        unsigned short* xb  = (unsigned short*)(ws + OFF_XB);
        convert_x_kernel<<<32768, 256, 0, stream>>>((const float4*)x, (uint4*)xb);
        prep_w_kernel<<<2048, 256, 0, stream>>>(Wi, wip);
        prep_w_kernel<<<2048, 256, 0, stream>>>(Wh, whp);
        lstm_scan_kernel<<<256, 512, 0, stream>>>(wip, whp, b, xb, hbuf, flags, out);
    } else {
        lstm_fallback_kernel<<<256, 256, 0, stream>>>(x, Wi, Wh, b, hbuf, flags, out);
    }
}